// Round 1
// baseline (82.651 us; speedup 1.0000x reference)
//
#include <hip/hip_runtime.h>

// StructuralAttention: 512 graphs x 256 nodes x 128 dim, fused QKV+attention.
// One block (512 threads, 8 waves) per graph. All MFMA = v_mfma_f32_16x16x16_bf16.
// LDS (128 KB): Ks bf16[256][128] @0 (swizzle (row&7)<<4), Vt bf16[128][256] @64K
// (swizzle (j&7)<<3); Wbuf bf16[128][128] overlaps Vt lower half (dead before Vt writes).

typedef float f32x4 __attribute__((ext_vector_type(4)));
typedef unsigned int u32x2 __attribute__((ext_vector_type(2)));
typedef unsigned int u32x4 __attribute__((ext_vector_type(4)));
typedef short s16x4 __attribute__((ext_vector_type(4)));

#define SCALE 0.088388347648318447f  // 1/sqrt(128)

__device__ __forceinline__ unsigned bf16pk(float a, float b) {
    unsigned ua = __builtin_bit_cast(unsigned, a);
    unsigned ub = __builtin_bit_cast(unsigned, b);
    ua += 0x7fffu + ((ua >> 16) & 1u);   // RNE to bf16
    ub += 0x7fffu + ((ub >> 16) & 1u);
    return (ua >> 16) | (ub & 0xffff0000u);
}

__device__ __forceinline__ unsigned short bf16s(float a) {
    unsigned ua = __builtin_bit_cast(unsigned, a);
    ua += 0x7fffu + ((ua >> 16) & 1u);
    return (unsigned short)(ua >> 16);
}

__device__ __forceinline__ f32x4 mfma16(u32x2 a, u32x2 b, f32x4 c) {
    return __builtin_amdgcn_mfma_f32_16x16x16bf16_1k(
        __builtin_bit_cast(s16x4, a), __builtin_bit_cast(s16x4, b), c, 0, 0, 0);
}

// LDS byte offsets (with bank-conflict swizzles; all reads/writes >= 8B stay aligned
// because XORed bits are >= bit3 with 8B-aligned bases)
__device__ __forceinline__ int ks_off(int row, int d) {        // K[row 0..255][d 0..127]
    return ((row << 8) + (d << 1)) ^ ((row & 7) << 4);
}
__device__ __forceinline__ int vt_off(int j, int k) {          // V^T[j 0..127][k 0..255]
    return (65536 + (j << 9) + (k << 1)) ^ ((j & 7) << 3);
}
__device__ __forceinline__ int w_off(int j, int d) {           // W[j 0..127][d 0..127]
    return (65536 + (j << 8) + (d << 1)) ^ ((j & 7) << 4);
}

extern "C" __global__ void __launch_bounds__(512, 2)
sattn(const float* __restrict__ x,
      const float* __restrict__ Wq, const float* __restrict__ bq,
      const float* __restrict__ Wk, const float* __restrict__ bk,
      const float* __restrict__ Wv, const float* __restrict__ bv,
      float* __restrict__ out)
{
    extern __shared__ char sm[];
    const int t    = threadIdx.x;
    const int lane = t & 63;
    const int w    = t >> 6;        // wave 0..7
    const int h    = lane & 15;
    const int g    = lane >> 4;     // lane group 0..3
    const int R0   = blockIdx.x << 8;   // graph base row
    const int wr0  = w << 5;            // wave base row within graph

    // ---- X fragments: X[wr0+16*rt+h][16*c+4g+i], fp32 global -> bf16 regs ----
    u32x2 xf[2][8];
#pragma unroll
    for (int rt = 0; rt < 2; ++rt) {
        const float* xr = x + (size_t)(R0 + wr0 + 16 * rt + h) * 128 + 4 * g;
#pragma unroll
        for (int c = 0; c < 8; ++c) {
            f32x4 v = *(const f32x4*)(xr + 16 * c);
            xf[rt][c] = (u32x2){ bf16pk(v.x, v.y), bf16pk(v.z, v.w) };
        }
    }

    // ---- weight staging helper: fp32 [128][128] -> bf16 swizzled LDS ----
    auto stageW = [&](const float* W) {
        const int j  = t >> 2;
        const int d0 = (t & 3) << 5;
        const float* src = W + j * 128 + d0;
#pragma unroll
        for (int m2 = 0; m2 < 4; ++m2) {
            f32x4 a = *(const f32x4*)(src + 8 * m2);
            f32x4 b = *(const f32x4*)(src + 8 * m2 + 4);
            u32x4 p = (u32x4){ bf16pk(a.x, a.y), bf16pk(a.z, a.w),
                               bf16pk(b.x, b.y), bf16pk(b.z, b.w) };
            *(u32x4*)(sm + w_off(j, d0 + 8 * m2)) = p;
        }
    };

    // ================= Q projection: Q^T = Wq * X^T (+bq), scaled, to regs ========
    stageW(Wq);
    __syncthreads();
    u32x2 qf[8][2];   // qf[jt][qc]: lane holds Q[wr0+16qc+h][16jt+4g+i]*SCALE
#pragma unroll
    for (int jt = 0; jt < 8; ++jt) {
        f32x4 b4 = *(const f32x4*)(bq + 16 * jt + 4 * g);
        f32x4 a0 = b4, a1 = b4;
#pragma unroll
        for (int c = 0; c < 8; ++c) {
            u32x2 wf = *(const u32x2*)(sm + w_off(h + 16 * jt, 16 * c + 4 * g));
            a0 = mfma16(wf, xf[0][c], a0);   // A=Wq, B=X^T -> D=Q^T
            a1 = mfma16(wf, xf[1][c], a1);
        }
        qf[jt][0] = (u32x2){ bf16pk(a0.x * SCALE, a0.y * SCALE), bf16pk(a0.z * SCALE, a0.w * SCALE) };
        qf[jt][1] = (u32x2){ bf16pk(a1.x * SCALE, a1.y * SCALE), bf16pk(a1.z * SCALE, a1.w * SCALE) };
    }
    __syncthreads();

    // ================= K projection: K = X * Wk^T (+bk) -> Ks (row-major) =========
    stageW(Wk);
    __syncthreads();
#pragma unroll
    for (int jt = 0; jt < 8; ++jt) {
        float bkj = bk[h + 16 * jt];
        f32x4 a0 = { bkj, bkj, bkj, bkj }, a1 = a0;
#pragma unroll
        for (int c = 0; c < 8; ++c) {
            u32x2 wf = *(const u32x2*)(sm + w_off(h + 16 * jt, 16 * c + 4 * g));
            a0 = mfma16(xf[0][c], wf, a0);   // A=X, B=Wk^T -> D=K
            a1 = mfma16(xf[1][c], wf, a1);
        }
#pragma unroll
        for (int r = 0; r < 4; ++r) {
            *(unsigned short*)(sm + ks_off(wr0 + 4 * g + r,      h + 16 * jt)) = bf16s(a0[r]);
            *(unsigned short*)(sm + ks_off(wr0 + 16 + 4 * g + r, h + 16 * jt)) = bf16s(a1[r]);
        }
    }
    __syncthreads();

    // ================= V projection: V = X * Wv^T (+bv) -> regs -> Vt =============
    stageW(Wv);
    __syncthreads();
    u32x2 vpk[2][8];
#pragma unroll
    for (int jt = 0; jt < 8; ++jt) {
        float bvj = bv[h + 16 * jt];
        f32x4 a0 = { bvj, bvj, bvj, bvj }, a1 = a0;
#pragma unroll
        for (int c = 0; c < 8; ++c) {
            u32x2 wf = *(const u32x2*)(sm + w_off(h + 16 * jt, 16 * c + 4 * g));
            a0 = mfma16(xf[0][c], wf, a0);
            a1 = mfma16(xf[1][c], wf, a1);
        }
        vpk[0][jt] = (u32x2){ bf16pk(a0.x, a0.y), bf16pk(a0.z, a0.w) };
        vpk[1][jt] = (u32x2){ bf16pk(a1.x, a1.y), bf16pk(a1.z, a1.w) };
    }
    __syncthreads();   // all waves done reading Wv before Vt overwrites it
#pragma unroll
    for (int jt = 0; jt < 8; ++jt) {
        *(u32x2*)(sm + vt_off(h + 16 * jt, wr0 + 4 * g))      = vpk[0][jt];
        *(u32x2*)(sm + vt_off(h + 16 * jt, wr0 + 16 + 4 * g)) = vpk[1][jt];
    }
    __syncthreads();

    // ================= attention: S^T = mfma(K, Q^T); P = exp(S); O += P*V ========
    f32x4 O[2][8];
#pragma unroll
    for (int qt = 0; qt < 2; ++qt)
#pragma unroll
        for (int jt = 0; jt < 8; ++jt)
            O[qt][jt] = (f32x4){ 0.f, 0.f, 0.f, 0.f };
    float ls0 = 0.f, ls1 = 0.f;

    for (int kc = 0; kc < 16; ++kc) {
        u32x2 kfr[8];
#pragma unroll
        for (int jt = 0; jt < 8; ++jt)
            kfr[jt] = *(const u32x2*)(sm + ks_off(16 * kc + h, 16 * jt + 4 * g));
        f32x4 s0 = { 0.f, 0.f, 0.f, 0.f }, s1 = s0;
#pragma unroll
        for (int jt = 0; jt < 8; ++jt) {
            s0 = mfma16(kfr[jt], qf[jt][0], s0);   // lane: S[q=h][k=16kc+4g+r]
            s1 = mfma16(kfr[jt], qf[jt][1], s1);
        }
        float e0[4], e1[4];
#pragma unroll
        for (int r = 0; r < 4; ++r) { e0[r] = __expf(s0[r]); e1[r] = __expf(s1[r]); }
        ls0 += e0[0] + e0[1] + e0[2] + e0[3];
        ls1 += e1[0] + e1[1] + e1[2] + e1[3];
        u32x2 pa0 = (u32x2){ bf16pk(e0[0], e0[1]), bf16pk(e0[2], e0[3]) };
        u32x2 pa1 = (u32x2){ bf16pk(e1[0], e1[1]), bf16pk(e1[2], e1[3]) };
#pragma unroll
        for (int jt = 0; jt < 8; ++jt) {
            u32x2 vf = *(const u32x2*)(sm + vt_off(h + 16 * jt, 16 * kc + 4 * g));
            O[0][jt] = mfma16(pa0, vf, O[0][jt]);
            O[1][jt] = mfma16(pa1, vf, O[1][jt]);
        }
    }

    // ================= epilogue: row-sum normalize, write fp32 =====================
    ls0 += __shfl_xor(ls0, 16); ls0 += __shfl_xor(ls0, 32);
    ls1 += __shfl_xor(ls1, 16); ls1 += __shfl_xor(ls1, 32);
    float li0 = 1.0f / ls0;     // valid for row h (qt=0)
    float li1 = 1.0f / ls1;     // valid for row h (qt=1)
#pragma unroll
    for (int r = 0; r < 4; ++r) {
        float ri0 = __shfl(li0, 4 * g + r);
        float ri1 = __shfl(li1, 4 * g + r);
        float* o0 = out + (size_t)(R0 + wr0 + 4 * g + r) * 128 + h;
        float* o1 = out + (size_t)(R0 + wr0 + 16 + 4 * g + r) * 128 + h;
#pragma unroll
        for (int jt = 0; jt < 8; ++jt) {
            o0[16 * jt] = O[0][jt][r] * ri0;
            o1[16 * jt] = O[1][jt][r] * ri1;
        }
    }
}

extern "C" void kernel_launch(void* const* d_in, const int* in_sizes, int n_in,
                              void* d_out, int out_size, void* d_ws, size_t ws_size,
                              hipStream_t stream) {
    const float* x  = (const float*)d_in[0];
    // d_in[1] = batch (int64) — contiguous equal segments, not needed
    const float* Wq = (const float*)d_in[2];
    const float* bq = (const float*)d_in[3];
    const float* Wk = (const float*)d_in[4];
    const float* bk = (const float*)d_in[5];
    const float* Wv = (const float*)d_in[6];
    const float* bv = (const float*)d_in[7];
    float* out = (float*)d_out;

    // allow 128 KB dynamic LDS (host-side call, idempotent, capture-safe)
    hipFuncSetAttribute((const void*)sattn,
                        hipFuncAttributeMaxDynamicSharedMemorySize, 131072);
    sattn<<<dim3(512), dim3(512), 131072, stream>>>(x, Wq, bq, Wk, bk, Wv, bv, out);
}